// Round 11
// baseline (610.046 us; speedup 1.0000x reference)
//
#include <hip/hip_runtime.h>

#define NN 100000
#define NE 1600000
#define NB 2
#define CH 8
#define HID 16
#define NTILES 98   // ceil(NN/1024)

typedef unsigned int uint;
typedef float f32x4 __attribute__((ext_vector_type(4)));

__device__ __forceinline__ float soft_clamp(float x) {
    float y = x * 1e-6f;
    return x * (1.0f - 0.33333333f * y * y);  // 1e6*tanh(x/1e6), |x| small
}
__device__ __forceinline__ float fast_tanh(float x) {
    float ax = fabsf(x);
    float t = __expf(-2.0f * ax);
    float r = (1.0f - t) / (1.0f + t);
    return copysignf(r, x);
}
__device__ __forceinline__ void load8(const float* __restrict__ p, float* x) {
    float4 a = ((const float4*)p)[0];
    float4 b = ((const float4*)p)[1];
    x[0]=a.x; x[1]=a.y; x[2]=a.z; x[3]=a.w; x[4]=b.x; x[5]=b.y; x[6]=b.z; x[7]=b.w;
}
__device__ __forceinline__ void store8(float* __restrict__ p, const float* x) {
    ((float4*)p)[0] = make_float4(x[0],x[1],x[2],x[3]);
    ((float4*)p)[1] = make_float4(x[4],x[5],x[6],x[7]);
}
__device__ __forceinline__ void f4w(float* p, float4 v){ p[0]=v.x; p[1]=v.y; p[2]=v.z; p[3]=v.w; }

__device__ __forceinline__ uint bfu(float x) {  // f32 -> bf16 bits (RNE)
    uint u = __float_as_uint(x);
    return (u + 0x7fffu + ((u >> 16) & 1u)) >> 16;
}
__device__ __forceinline__ float ubf(uint u) { return __uint_as_float(u << 16); }

__device__ __forceinline__ ushort f2h(float x) {
    _Float16 h = (_Float16)x;
    union { _Float16 h; ushort u; } c; c.h = h; return c.u;
}
__device__ __forceinline__ float h2f(uint u) {
    union { ushort u; _Float16 h; } c; c.u = (ushort)u; return (float)c.h;
}
__device__ __forceinline__ float dot8h(uint4 a, uint4 b) {
    const uint* pa = &a.x; const uint* pb = &b.x;
    float s = 0.0f;
#pragma unroll
    for (int i = 0; i < 4; i++) {
        s += h2f(pa[i] & 0xffffu) * h2f(pb[i] & 0xffffu);
        s += h2f(pa[i] >> 16)     * h2f(pb[i] >> 16);
    }
    return s;
}

// streaming layer-1 accumulate: h[j] += x_i * w[(base+i)*HID + j] for 8 f16 inputs
__device__ __forceinline__ void acc8(float* h, uint4 v, const float* __restrict__ w) {
    const uint* p = &v.x;
#pragma unroll
    for (int i = 0; i < 4; i++) {
        float x0 = h2f(p[i] & 0xffffu), x1 = h2f(p[i] >> 16);
#pragma unroll
        for (int j = 0; j < HID; j++) h[j] += x0 * w[(2*i)*HID + j];
#pragma unroll
        for (int j = 0; j < HID; j++) h[j] += x1 * w[(2*i+1)*HID + j];
    }
}

// ---------------- att MLP per node + packed layouts ----------------
// S[n,b] (64B line): {nodes 8f16, a_key 8f16, a_query 8f16, pad 16B}
// T[n,b] (64B line): {nodes 8f16, b_key 8f16, b_query 8f16, pad 16B}
// nodesP[n] (64B): {b0: 8 f32, b1: 8 f32}
__global__ void __launch_bounds__(256)
att_pack_kernel(const float* __restrict__ nodes,
                const float* __restrict__ w1, const float* __restrict__ b1,
                const float* __restrict__ w2, const float* __restrict__ b2,
                uint4* __restrict__ S, uint4* __restrict__ T,
                float4* __restrict__ nodesP) {
    __shared__ float sw1[CH*HID], sb1[HID], sw2[HID*32], sb2[32];
    int tid = threadIdx.x;
    for (int i = tid; i < CH*HID; i += 256) sw1[i] = w1[i];
    for (int i = tid; i < HID; i += 256) sb1[i] = b1[i];
    for (int i = tid; i < HID*32; i += 256) sw2[i] = w2[i];
    for (int i = tid; i < 32; i += 256) sb2[i] = b2[i];
    __syncthreads();
    int n = blockIdx.x * 256 + tid;
    if (n >= NN) return;
    int b = blockIdx.y;
    size_t base = (size_t)b * NN + n;

    float x[CH];
    load8(nodes + base * CH, x);
    nodesP[(size_t)n*4 + b*2]     = make_float4(x[0],x[1],x[2],x[3]);
    nodesP[(size_t)n*4 + b*2 + 1] = make_float4(x[4],x[5],x[6],x[7]);

    float h[HID];
#pragma unroll
    for (int j = 0; j < HID; j++) {
        float acc = sb1[j];
#pragma unroll
        for (int i = 0; i < CH; i++) acc += x[i] * sw1[i*HID + j];
        h[j] = fast_tanh(acc);
    }
    float o[32];
#pragma unroll
    for (int k = 0; k < 32; k++) {
        float acc = sb2[k];
#pragma unroll
        for (int j = 0; j < HID; j++) acc += h[j] * sw2[j*32 + k];
        o[k] = acc;
    }
    uint4 nx, ak, aq, bk, bq;
    nx.x=f2h(x[0]) |(f2h(x[1]) <<16); nx.y=f2h(x[2]) |(f2h(x[3]) <<16);
    nx.z=f2h(x[4]) |(f2h(x[5]) <<16); nx.w=f2h(x[6]) |(f2h(x[7]) <<16);
    ak.x=f2h(o[0]) |(f2h(o[1]) <<16); ak.y=f2h(o[2]) |(f2h(o[3]) <<16);
    ak.z=f2h(o[4]) |(f2h(o[5]) <<16); ak.w=f2h(o[6]) |(f2h(o[7]) <<16);
    aq.x=f2h(o[8]) |(f2h(o[9]) <<16); aq.y=f2h(o[10])|(f2h(o[11])<<16);
    aq.z=f2h(o[12])|(f2h(o[13])<<16); aq.w=f2h(o[14])|(f2h(o[15])<<16);
    bk.x=f2h(o[16])|(f2h(o[17])<<16); bk.y=f2h(o[18])|(f2h(o[19])<<16);
    bk.z=f2h(o[20])|(f2h(o[21])<<16); bk.w=f2h(o[22])|(f2h(o[23])<<16);
    bq.x=f2h(o[24])|(f2h(o[25])<<16); bq.y=f2h(o[26])|(f2h(o[27])<<16);
    bq.z=f2h(o[28])|(f2h(o[29])<<16); bq.w=f2h(o[30])|(f2h(o[31])<<16);
    size_t sl = (size_t)n*8 + b*4;   // uint4 units; 64B per (n,b)
    S[sl+0] = nx; S[sl+1] = ak; S[sl+2] = aq;
    T[sl+0] = nx; T[sl+1] = bk; T[sl+2] = bq;
}

// ---------------- CSR build ----------------
__global__ void __launch_bounds__(256)
hist_rank_kernel(const int* __restrict__ src, const int* __restrict__ tgt,
                 int* __restrict__ cntA, int* __restrict__ cntB,
                 int* __restrict__ rankA, int* __restrict__ rankB) {
    int e = blockIdx.x * 256 + threadIdx.x;
    if (e >= NE) return;
    rankA[e] = atomicAdd(&cntA[src[e]], 1);
    rankB[e] = atomicAdd(&cntB[tgt[e]], 1);
}

__global__ void __launch_bounds__(256)
scan_part_kernel(const int* __restrict__ cnt, int* __restrict__ part) {
    int y = blockIdx.y;
    const int* c = cnt + (size_t)y * NN;
    __shared__ int s[256];
    int t = threadIdx.x, bx = blockIdx.x;
    int base = bx * 1024 + t * 4;
    int sum = 0;
#pragma unroll
    for (int k = 0; k < 4; k++) { int i = base + k; sum += (i < NN) ? c[i] : 0; }
    s[t] = sum; __syncthreads();
    for (int off = 128; off > 0; off >>= 1) { if (t < off) s[t] += s[t + off]; __syncthreads(); }
    if (t == 0) part[y * 256 + bx] = s[0];
}

__global__ void __launch_bounds__(256)
scan_top_kernel(int* __restrict__ part, int* __restrict__ rowA, int* __restrict__ rowB) {
    int y = blockIdx.y; int t = threadIdx.x;
    __shared__ int s[256];
    int v = (t < NTILES) ? part[y * 256 + t] : 0;
    s[t] = v; __syncthreads();
    for (int off = 1; off < 256; off <<= 1) {
        int x = (t >= off) ? s[t - off] : 0;
        __syncthreads();
        s[t] += x;
        __syncthreads();
    }
    part[y * 256 + t] = t ? s[t - 1] : 0;
    if (t == 0) (y ? rowB : rowA)[NN] = NE;
}

__global__ void __launch_bounds__(256)
scan_down_kernel(const int* __restrict__ cnt, const int* __restrict__ part,
                 int* __restrict__ rowA, int* __restrict__ rowB) {
    int y = blockIdx.y;
    const int* c = cnt + (size_t)y * NN;
    int* row = y ? rowB : rowA;
    __shared__ int s[256];
    int t = threadIdx.x, bx = blockIdx.x;
    int base = bx * 1024 + t * 4;
    int v[4]; int tsum = 0;
#pragma unroll
    for (int k = 0; k < 4; k++) { int i = base + k; v[k] = (i < NN) ? c[i] : 0; tsum += v[k]; }
    s[t] = tsum; __syncthreads();
    for (int off = 1; off < 256; off <<= 1) {
        int x = (t >= off) ? s[t - off] : 0;
        __syncthreads();
        s[t] += x;
        __syncthreads();
    }
    int run = part[y * 256 + bx] + s[t] - tsum;
#pragma unroll
    for (int k = 0; k < 4; k++) {
        int i = base + k;
        if (i < NN) row[i] = run;
        run += v[k];
    }
}

// ---------------- edge: 1 thread = 1 edge-batch; streaming layer-1; fused CSR fill ----------------
// Exactly 2 random 64B line-fills per thread: S[s,b], T[t,b].
// recA[e] 64B: [b0: {la, ma01, ma23, ma45}, {ma67,0,0,0} | b1: same]; recB with lb/m_b.
__global__ void __launch_bounds__(256, 2)
edge_kernel(const uint4* __restrict__ S, const uint4* __restrict__ T,
            const float* __restrict__ edges,
            const int* __restrict__ src, const int* __restrict__ tgt,
            const int* __restrict__ rowA, const int* __restrict__ rowB,
            const int* __restrict__ rankA, const int* __restrict__ rankB,
            int* __restrict__ eidA, int* __restrict__ eidB,
            const float* __restrict__ w1, const float* __restrict__ b1,
            const float* __restrict__ w2, const float* __restrict__ b2,
            float* __restrict__ out_edges,
            uint4* __restrict__ recA, uint4* __restrict__ recB) {
    __shared__ float sw1[24*HID], sb1[HID], sw2[HID*24], sb2[24];
    int tid = threadIdx.x;
    for (int i = tid; i < 24*HID; i += 256) sw1[i] = w1[i];
    for (int i = tid; i < HID; i += 256) sb1[i] = b1[i];
    for (int i = tid; i < HID*24; i += 256) sw2[i] = w2[i];
    for (int i = tid; i < 24; i += 256) sb2[i] = b2[i];
    __syncthreads();
    int b = blockIdx.x;
    int e = blockIdx.y * 256 + tid;   // NE % 256 == 0
    int s = src[e], t = tgt[e];
    const float scale = 0.35355339059327373f;

    if (b == 0) {   // fused CSR fill (once per edge)
        eidA[rowA[s] + rankA[e]] = e;
        eidB[rowB[t] + rankB[e]] = e;
    }

    size_t sl = (size_t)s*8 + b*4, tl = (size_t)t*8 + b*4;
    uint4 sn = S[sl], ak = S[sl+1], aq = S[sl+2];
    uint4 tn = T[tl], bk = T[tl+1], bq = T[tl+2];
    f32x4 e0, e1;
    {
        const f32x4* ep = (const f32x4*)(edges + ((size_t)b*NE + e)*CH);
        e0 = __builtin_nontemporal_load(ep);
        e1 = __builtin_nontemporal_load(ep + 1);
    }

    float la = scale * dot8h(aq, bk);   // a_query(s)·b_key(t); ak..bq die here
    float lb = scale * dot8h(bq, ak);   // b_query(t)·a_key(s)

    // layer 1, streaming (no in[24] materialization)
    float h[HID];
#pragma unroll
    for (int j = 0; j < HID; j++) h[j] = sb1[j];
    acc8(h, sn, sw1);            // inputs 0..7  (src node, f16)
    acc8(h, tn, sw1 + 8*HID);    // inputs 8..15 (tgt node, f16)
    float ef[8];
    ef[0]=e0.x; ef[1]=e0.y; ef[2]=e0.z; ef[3]=e0.w;
    ef[4]=e1.x; ef[5]=e1.y; ef[6]=e1.z; ef[7]=e1.w;
#pragma unroll
    for (int i = 0; i < 8; i++) {
#pragma unroll
        for (int j = 0; j < HID; j++) h[j] += ef[i] * sw1[(16+i)*HID + j];
    }
#pragma unroll
    for (int j = 0; j < HID; j++) h[j] = fast_tanh(h[j]);

    float m[24];
#pragma unroll
    for (int k = 0; k < 24; k++) {
        float acc = sb2[k];
#pragma unroll
        for (int j = 0; j < HID; j++) acc += h[j] * sw2[j*24 + k];
        m[k] = acc;
    }

    {   // non-temporal stream out
        f32x4* op = (f32x4*)(out_edges + ((size_t)b*NE + e)*CH);
        f32x4 o0, o1;
        o0.x = soft_clamp(ef[0] + m[16]); o0.y = soft_clamp(ef[1] + m[17]);
        o0.z = soft_clamp(ef[2] + m[18]); o0.w = soft_clamp(ef[3] + m[19]);
        o1.x = soft_clamp(ef[4] + m[20]); o1.y = soft_clamp(ef[5] + m[21]);
        o1.z = soft_clamp(ef[6] + m[22]); o1.w = soft_clamp(ef[7] + m[23]);
        __builtin_nontemporal_store(o0, op);
        __builtin_nontemporal_store(o1, op + 1);
    }

    recA[(size_t)e*4 + b*2] = make_uint4(__float_as_uint(la),
                                         bfu(m[0]) | (bfu(m[1]) << 16),
                                         bfu(m[2]) | (bfu(m[3]) << 16),
                                         bfu(m[4]) | (bfu(m[5]) << 16));
    recA[(size_t)e*4 + b*2 + 1] = make_uint4(bfu(m[6]) | (bfu(m[7]) << 16), 0u, 0u, 0u);
    recB[(size_t)e*4 + b*2] = make_uint4(__float_as_uint(lb),
                                         bfu(m[8])  | (bfu(m[9])  << 16),
                                         bfu(m[10]) | (bfu(m[11]) << 16),
                                         bfu(m[12]) | (bfu(m[13]) << 16));
    recB[(size_t)e*4 + b*2 + 1] = make_uint4(bfu(m[14]) | (bfu(m[15]) << 16), 0u, 0u, 0u);
}

// ---------------- node: 1 thread = 1 (node,batch); pair threads share rec lines ----------------
__device__ __forceinline__ void aggregate1(int beg, int end, const int* __restrict__ eid,
                                           const uint4* __restrict__ rec, int boff,
                                           float* __restrict__ o) {
    float mx = -1e30f, den = 0.0f, num[CH];
#pragma unroll
    for (int c = 0; c < CH; c++) num[c] = 0.0f;
    for (int i = beg; i < end; ++i) {
        int e = eid[i];
        const uint4* P = rec + (size_t)e*4 + boff;
        uint4 q0 = P[0], q1 = P[1];
        float l = __uint_as_float(q0.x);
        float nm = fmaxf(mx, l);
        float r = __expf(mx - nm), w = __expf(l - nm);
        mx = nm; den = den * r + w;
        float mm[CH];
        mm[0]=ubf(q0.y&0xffffu); mm[1]=ubf(q0.y>>16);
        mm[2]=ubf(q0.z&0xffffu); mm[3]=ubf(q0.z>>16);
        mm[4]=ubf(q0.w&0xffffu); mm[5]=ubf(q0.w>>16);
        mm[6]=ubf(q1.x&0xffffu); mm[7]=ubf(q1.x>>16);
#pragma unroll
        for (int c = 0; c < CH; c++) num[c] = num[c] * r + w * mm[c];
    }
    float inv = 1.0f / (den + 1e-10f);
#pragma unroll
    for (int c = 0; c < CH; c++) o[c] = num[c] * inv;
}

__global__ void __launch_bounds__(256)
node_kernel(const float4* __restrict__ nodesP,
            const int* __restrict__ rowA, const int* __restrict__ rowB,
            const int* __restrict__ eidA, const int* __restrict__ eidB,
            const uint4* __restrict__ recA, const uint4* __restrict__ recB,
            const float* __restrict__ w1, const float* __restrict__ b1,
            const float* __restrict__ w2, const float* __restrict__ b2,
            float* __restrict__ out_nodes) {
    __shared__ float sw1[24*HID], sb1[HID], sw2[HID*CH], sb2[CH];
    int tid = threadIdx.x;
    for (int i = tid; i < 24*HID; i += 256) sw1[i] = w1[i];
    for (int i = tid; i < HID; i += 256) sb1[i] = b1[i];
    for (int i = tid; i < HID*CH; i += 256) sw2[i] = w2[i];
    for (int i = tid; i < CH; i += 256) sb2[i] = b2[i];
    __syncthreads();
    int g = blockIdx.x * 256 + tid;
    int n = g >> 1, b = g & 1;      // pair threads (b=0,1) share rec lines / eid reads
    if (n >= NN) return;

    float in[24];
    float4 np0 = nodesP[(size_t)n*4 + b*2], np1 = nodesP[(size_t)n*4 + b*2 + 1];
    f4w(in, np0); f4w(in + 4, np1);

    aggregate1(rowA[n], rowA[n+1], eidA, recA, b*2, in + 8);
    aggregate1(rowB[n], rowB[n+1], eidB, recB, b*2, in + 16);

    float h[HID];
#pragma unroll
    for (int j = 0; j < HID; j++) {
        float acc = sb1[j];
#pragma unroll
        for (int i = 0; i < 24; i++) acc += in[i] * sw1[i*HID + j];
        h[j] = fast_tanh(acc);
    }
    float no[CH];
#pragma unroll
    for (int k = 0; k < CH; k++) {
        float acc = sb2[k];
#pragma unroll
        for (int j = 0; j < HID; j++) acc += h[j] * sw2[j*CH + k];
        no[k] = soft_clamp(in[k] + acc);
    }
    store8(out_nodes + ((size_t)b*NN + n)*CH, no);
}

extern "C" void kernel_launch(void* const* d_in, const int* in_sizes, int n_in,
                              void* d_out, int out_size, void* d_ws, size_t ws_size,
                              hipStream_t stream) {
    const float* nodes  = (const float*)d_in[0];
    const float* edges  = (const float*)d_in[1];
    const float* msg_w1 = (const float*)d_in[2];
    const float* msg_b1 = (const float*)d_in[3];
    const float* msg_w2 = (const float*)d_in[4];
    const float* msg_b2 = (const float*)d_in[5];
    const float* att_w1 = (const float*)d_in[6];
    const float* att_b1 = (const float*)d_in[7];
    const float* att_w2 = (const float*)d_in[8];
    const float* att_b2 = (const float*)d_in[9];
    const float* upd_w1 = (const float*)d_in[10];
    const float* upd_b1 = (const float*)d_in[11];
    const float* upd_w2 = (const float*)d_in[12];
    const float* upd_b2 = (const float*)d_in[13];
    const int*   sources = (const int*)d_in[14];
    const int*   targets = (const int*)d_in[15];

    float* out       = (float*)d_out;
    float* out_nodes = out;
    float* out_edges = out + (size_t)NB * NN * CH;

    char* wp = (char*)d_ws;
    size_t off = 0;
    auto take = [&](size_t bytes) -> char* {
        char* p = wp + off;
        off = (off + bytes + 255) & ~(size_t)255;
        return p;
    };
    uint4*  S      = (uint4*)take((size_t)NN * NB * 64);
    uint4*  T      = (uint4*)take((size_t)NN * NB * 64);
    float4* nodesP = (float4*)take((size_t)NN * 64);
    int*    cnt    = (int*)take((size_t)2 * NN * 4);
    int*    rowA   = (int*)take((size_t)(NN + 1) * 4);
    int*    rowB   = (int*)take((size_t)(NN + 1) * 4);
    int*    part   = (int*)take((size_t)2 * 256 * 4);
    int*    rankA  = (int*)take((size_t)NE * 4);
    int*    rankB  = (int*)take((size_t)NE * 4);
    int*    eidA   = (int*)take((size_t)NE * 4);
    int*    eidB   = (int*)take((size_t)NE * 4);
    uint4*  recA   = (uint4*)take((size_t)NE * 64);
    uint4*  recB   = (uint4*)take((size_t)NE * 64);
    int* cntA = cnt, *cntB = cnt + NN;

    dim3 gn((NN + 255) / 256, NB);
    dim3 gn2((2*NN + 255) / 256);
    dim3 ge1((NE + 255) / 256);
    dim3 geb(NB, NE / 256);          // batch fastest -> adjacent dispatch of (0,k),(1,k)
    dim3 gs(NTILES, 2);
    dim3 gt(1, 2);

    (void)hipMemsetAsync(cnt, 0, (size_t)2 * NN * 4, stream);
    att_pack_kernel<<<gn, 256, 0, stream>>>(nodes, att_w1, att_b1, att_w2, att_b2,
                                            S, T, nodesP);
    hist_rank_kernel<<<ge1, 256, 0, stream>>>(sources, targets, cntA, cntB, rankA, rankB);
    scan_part_kernel<<<gs, 256, 0, stream>>>(cnt, part);
    scan_top_kernel<<<gt, 256, 0, stream>>>(part, rowA, rowB);
    scan_down_kernel<<<gs, 256, 0, stream>>>(cnt, part, rowA, rowB);
    edge_kernel<<<geb, 256, 0, stream>>>(S, T, edges, sources, targets,
                                         rowA, rowB, rankA, rankB, eidA, eidB,
                                         msg_w1, msg_b1, msg_w2, msg_b2,
                                         out_edges, recA, recB);
    node_kernel<<<gn2, 256, 0, stream>>>(nodesP, rowA, rowB, eidA, eidB, recA, recB,
                                         upd_w1, upd_b1, upd_w2, upd_b2, out_nodes);
}

// Round 12
// 544.965 us; speedup vs baseline: 1.1194x; 1.1194x over previous
//
#include <hip/hip_runtime.h>

#define NN 100000
#define NE 1600000
#define NB 2
#define CH 8
#define HID 16
#define NTILES 98   // ceil(NN/1024)

typedef unsigned int uint;
typedef float f32x4 __attribute__((ext_vector_type(4)));

__device__ __forceinline__ float soft_clamp(float x) {
    float y = x * 1e-6f;
    return x * (1.0f - 0.33333333f * y * y);  // 1e6*tanh(x/1e6), |x| small
}
__device__ __forceinline__ float fast_tanh(float x) {
    float ax = fabsf(x);
    float t = __expf(-2.0f * ax);
    float r = (1.0f - t) / (1.0f + t);
    return copysignf(r, x);
}
__device__ __forceinline__ void load8(const float* __restrict__ p, float* x) {
    float4 a = ((const float4*)p)[0];
    float4 b = ((const float4*)p)[1];
    x[0]=a.x; x[1]=a.y; x[2]=a.z; x[3]=a.w; x[4]=b.x; x[5]=b.y; x[6]=b.z; x[7]=b.w;
}
__device__ __forceinline__ void store8(float* __restrict__ p, const float* x) {
    ((float4*)p)[0] = make_float4(x[0],x[1],x[2],x[3]);
    ((float4*)p)[1] = make_float4(x[4],x[5],x[6],x[7]);
}
__device__ __forceinline__ void f4w(float* p, float4 v){ p[0]=v.x; p[1]=v.y; p[2]=v.z; p[3]=v.w; }

__device__ __forceinline__ uint bfu(float x) {  // f32 -> bf16 bits (RNE)
    uint u = __float_as_uint(x);
    return (u + 0x7fffu + ((u >> 16) & 1u)) >> 16;
}
__device__ __forceinline__ float ubf(uint u) { return __uint_as_float(u << 16); }

__device__ __forceinline__ ushort f2h(float x) {
    _Float16 h = (_Float16)x;
    union { _Float16 h; ushort u; } c; c.h = h; return c.u;
}
__device__ __forceinline__ float h2f(uint u) {
    union { ushort u; _Float16 h; } c; c.u = (ushort)u; return (float)c.h;
}
__device__ __forceinline__ float dot8h(uint4 a, uint4 b) {
    const uint* pa = &a.x; const uint* pb = &b.x;
    float s = 0.0f;
#pragma unroll
    for (int i = 0; i < 4; i++) {
        s += h2f(pa[i] & 0xffffu) * h2f(pb[i] & 0xffffu);
        s += h2f(pa[i] >> 16)     * h2f(pb[i] >> 16);
    }
    return s;
}

// streaming layer-1 accumulate: h[j] += x_i * w[(base+i)*HID + j] for 8 f16 inputs
__device__ __forceinline__ void acc8(float* h, uint4 v, const float* __restrict__ w) {
    const uint* p = &v.x;
#pragma unroll
    for (int i = 0; i < 4; i++) {
        float x0 = h2f(p[i] & 0xffffu), x1 = h2f(p[i] >> 16);
#pragma unroll
        for (int j = 0; j < HID; j++) h[j] += x0 * w[(2*i)*HID + j];
#pragma unroll
        for (int j = 0; j < HID; j++) h[j] += x1 * w[(2*i+1)*HID + j];
    }
}

// ---------------- att MLP per node + packed layouts ----------------
// S[n,b] (64B line): {nodes 8f16, a_key 8f16, a_query 8f16, pad 16B}
// T[n,b] (64B line): {nodes 8f16, b_key 8f16, b_query 8f16, pad 16B}
// nodesP[n] (64B): {b0: 8 f32, b1: 8 f32}
__global__ void __launch_bounds__(256)
att_pack_kernel(const float* __restrict__ nodes,
                const float* __restrict__ w1, const float* __restrict__ b1,
                const float* __restrict__ w2, const float* __restrict__ b2,
                uint4* __restrict__ S, uint4* __restrict__ T,
                float4* __restrict__ nodesP) {
    __shared__ float sw1[CH*HID], sb1[HID], sw2[HID*32], sb2[32];
    int tid = threadIdx.x;
    for (int i = tid; i < CH*HID; i += 256) sw1[i] = w1[i];
    for (int i = tid; i < HID; i += 256) sb1[i] = b1[i];
    for (int i = tid; i < HID*32; i += 256) sw2[i] = w2[i];
    for (int i = tid; i < 32; i += 256) sb2[i] = b2[i];
    __syncthreads();
    int n = blockIdx.x * 256 + tid;
    if (n >= NN) return;
    int b = blockIdx.y;
    size_t base = (size_t)b * NN + n;

    float x[CH];
    load8(nodes + base * CH, x);
    nodesP[(size_t)n*4 + b*2]     = make_float4(x[0],x[1],x[2],x[3]);
    nodesP[(size_t)n*4 + b*2 + 1] = make_float4(x[4],x[5],x[6],x[7]);

    float h[HID];
#pragma unroll
    for (int j = 0; j < HID; j++) {
        float acc = sb1[j];
#pragma unroll
        for (int i = 0; i < CH; i++) acc += x[i] * sw1[i*HID + j];
        h[j] = fast_tanh(acc);
    }
    float o[32];
#pragma unroll
    for (int k = 0; k < 32; k++) {
        float acc = sb2[k];
#pragma unroll
        for (int j = 0; j < HID; j++) acc += h[j] * sw2[j*32 + k];
        o[k] = acc;
    }
    uint4 nx, ak, aq, bk, bq;
    nx.x=f2h(x[0]) |(f2h(x[1]) <<16); nx.y=f2h(x[2]) |(f2h(x[3]) <<16);
    nx.z=f2h(x[4]) |(f2h(x[5]) <<16); nx.w=f2h(x[6]) |(f2h(x[7]) <<16);
    ak.x=f2h(o[0]) |(f2h(o[1]) <<16); ak.y=f2h(o[2]) |(f2h(o[3]) <<16);
    ak.z=f2h(o[4]) |(f2h(o[5]) <<16); ak.w=f2h(o[6]) |(f2h(o[7]) <<16);
    aq.x=f2h(o[8]) |(f2h(o[9]) <<16); aq.y=f2h(o[10])|(f2h(o[11])<<16);
    aq.z=f2h(o[12])|(f2h(o[13])<<16); aq.w=f2h(o[14])|(f2h(o[15])<<16);
    bk.x=f2h(o[16])|(f2h(o[17])<<16); bk.y=f2h(o[18])|(f2h(o[19])<<16);
    bk.z=f2h(o[20])|(f2h(o[21])<<16); bk.w=f2h(o[22])|(f2h(o[23])<<16);
    bq.x=f2h(o[24])|(f2h(o[25])<<16); bq.y=f2h(o[26])|(f2h(o[27])<<16);
    bq.z=f2h(o[28])|(f2h(o[29])<<16); bq.w=f2h(o[30])|(f2h(o[31])<<16);
    size_t sl = (size_t)n*8 + b*4;   // uint4 units; 64B per (n,b)
    S[sl+0] = nx; S[sl+1] = ak; S[sl+2] = aq;
    T[sl+0] = nx; T[sl+1] = bk; T[sl+2] = bq;
}

// ---------------- CSR build ----------------
__global__ void __launch_bounds__(256)
hist_rank_kernel(const int* __restrict__ src, const int* __restrict__ tgt,
                 int* __restrict__ cntA, int* __restrict__ cntB,
                 int* __restrict__ rankA, int* __restrict__ rankB) {
    int e = blockIdx.x * 256 + threadIdx.x;
    if (e >= NE) return;
    rankA[e] = atomicAdd(&cntA[src[e]], 1);
    rankB[e] = atomicAdd(&cntB[tgt[e]], 1);
}

__global__ void __launch_bounds__(256)
scan_part_kernel(const int* __restrict__ cnt, int* __restrict__ part) {
    int y = blockIdx.y;
    const int* c = cnt + (size_t)y * NN;
    __shared__ int s[256];
    int t = threadIdx.x, bx = blockIdx.x;
    int base = bx * 1024 + t * 4;
    int sum = 0;
#pragma unroll
    for (int k = 0; k < 4; k++) { int i = base + k; sum += (i < NN) ? c[i] : 0; }
    s[t] = sum; __syncthreads();
    for (int off = 128; off > 0; off >>= 1) { if (t < off) s[t] += s[t + off]; __syncthreads(); }
    if (t == 0) part[y * 256 + bx] = s[0];
}

__global__ void __launch_bounds__(256)
scan_top_kernel(int* __restrict__ part, int* __restrict__ rowA, int* __restrict__ rowB) {
    int y = blockIdx.y; int t = threadIdx.x;
    __shared__ int s[256];
    int v = (t < NTILES) ? part[y * 256 + t] : 0;
    s[t] = v; __syncthreads();
    for (int off = 1; off < 256; off <<= 1) {
        int x = (t >= off) ? s[t - off] : 0;
        __syncthreads();
        s[t] += x;
        __syncthreads();
    }
    part[y * 256 + t] = t ? s[t - 1] : 0;
    if (t == 0) (y ? rowB : rowA)[NN] = NE;
}

__global__ void __launch_bounds__(256)
scan_down_kernel(const int* __restrict__ cnt, const int* __restrict__ part,
                 int* __restrict__ rowA, int* __restrict__ rowB) {
    int y = blockIdx.y;
    const int* c = cnt + (size_t)y * NN;
    int* row = y ? rowB : rowA;
    __shared__ int s[256];
    int t = threadIdx.x, bx = blockIdx.x;
    int base = bx * 1024 + t * 4;
    int v[4]; int tsum = 0;
#pragma unroll
    for (int k = 0; k < 4; k++) { int i = base + k; v[k] = (i < NN) ? c[i] : 0; tsum += v[k]; }
    s[t] = tsum; __syncthreads();
    for (int off = 1; off < 256; off <<= 1) {
        int x = (t >= off) ? s[t - off] : 0;
        __syncthreads();
        s[t] += x;
        __syncthreads();
    }
    int run = part[y * 256 + bx] + s[t] - tsum;
#pragma unroll
    for (int k = 0; k < 4; k++) {
        int i = base + k;
        if (i < NN) row[i] = run;
        run += v[k];
    }
}

__global__ void __launch_bounds__(256)
fill_kernel(const int* __restrict__ src, const int* __restrict__ tgt,
            const int* __restrict__ rowA, const int* __restrict__ rowB,
            const int* __restrict__ rankA, const int* __restrict__ rankB,
            int* __restrict__ eidA, int* __restrict__ eidB) {
    int e = blockIdx.x * 256 + threadIdx.x;
    if (e >= NE) return;
    eidA[rowA[src[e]] + rankA[e]] = e;
    eidB[rowB[tgt[e]] + rankB[e]] = e;
}

// ---------------- edge: 1 thread = 1 edge-batch; streaming layer-1; batch = blockIdx.x ----------------
// Exactly 2 random 64B line-fills per thread: S[s,b], T[t,b].
// recA[e] 64B: [b0: {la, ma01, ma23, ma45}, {ma67,0,0,0} | b1: same]; recB with lb/m_b.
__global__ void __launch_bounds__(256, 2)
edge_kernel(const uint4* __restrict__ S, const uint4* __restrict__ T,
            const float* __restrict__ edges,
            const int* __restrict__ src, const int* __restrict__ tgt,
            const float* __restrict__ w1, const float* __restrict__ b1,
            const float* __restrict__ w2, const float* __restrict__ b2,
            float* __restrict__ out_edges,
            uint4* __restrict__ recA, uint4* __restrict__ recB) {
    __shared__ float sw1[24*HID], sb1[HID], sw2[HID*24], sb2[24];
    int tid = threadIdx.x;
    for (int i = tid; i < 24*HID; i += 256) sw1[i] = w1[i];
    for (int i = tid; i < HID; i += 256) sb1[i] = b1[i];
    for (int i = tid; i < HID*24; i += 256) sw2[i] = w2[i];
    for (int i = tid; i < 24; i += 256) sb2[i] = b2[i];
    __syncthreads();
    int b = blockIdx.x;
    int e = blockIdx.y * 256 + tid;   // NE % 256 == 0
    int s = src[e], t = tgt[e];
    const float scale = 0.35355339059327373f;

    size_t sl = (size_t)s*8 + b*4, tl = (size_t)t*8 + b*4;
    uint4 sn = S[sl], ak = S[sl+1], aq = S[sl+2];
    uint4 tn = T[tl], bk = T[tl+1], bq = T[tl+2];
    f32x4 e0, e1;
    {
        const f32x4* ep = (const f32x4*)(edges + ((size_t)b*NE + e)*CH);
        e0 = __builtin_nontemporal_load(ep);
        e1 = __builtin_nontemporal_load(ep + 1);
    }

    float la = scale * dot8h(aq, bk);   // a_query(s)·b_key(t); ak..bq die here
    float lb = scale * dot8h(bq, ak);   // b_query(t)·a_key(s)

    // layer 1, streaming (no in[24] materialization)
    float h[HID];
#pragma unroll
    for (int j = 0; j < HID; j++) h[j] = sb1[j];
    acc8(h, sn, sw1);            // inputs 0..7  (src node, f16)
    acc8(h, tn, sw1 + 8*HID);    // inputs 8..15 (tgt node, f16)
    float ef[8];
    ef[0]=e0.x; ef[1]=e0.y; ef[2]=e0.z; ef[3]=e0.w;
    ef[4]=e1.x; ef[5]=e1.y; ef[6]=e1.z; ef[7]=e1.w;
#pragma unroll
    for (int i = 0; i < 8; i++) {
#pragma unroll
        for (int j = 0; j < HID; j++) h[j] += ef[i] * sw1[(16+i)*HID + j];
    }
#pragma unroll
    for (int j = 0; j < HID; j++) h[j] = fast_tanh(h[j]);

    float m[24];
#pragma unroll
    for (int k = 0; k < 24; k++) {
        float acc = sb2[k];
#pragma unroll
        for (int j = 0; j < HID; j++) acc += h[j] * sw2[j*24 + k];
        m[k] = acc;
    }

    {   // non-temporal stream out
        f32x4* op = (f32x4*)(out_edges + ((size_t)b*NE + e)*CH);
        f32x4 o0, o1;
        o0.x = soft_clamp(ef[0] + m[16]); o0.y = soft_clamp(ef[1] + m[17]);
        o0.z = soft_clamp(ef[2] + m[18]); o0.w = soft_clamp(ef[3] + m[19]);
        o1.x = soft_clamp(ef[4] + m[20]); o1.y = soft_clamp(ef[5] + m[21]);
        o1.z = soft_clamp(ef[6] + m[22]); o1.w = soft_clamp(ef[7] + m[23]);
        __builtin_nontemporal_store(o0, op);
        __builtin_nontemporal_store(o1, op + 1);
    }

    recA[(size_t)e*4 + b*2] = make_uint4(__float_as_uint(la),
                                         bfu(m[0]) | (bfu(m[1]) << 16),
                                         bfu(m[2]) | (bfu(m[3]) << 16),
                                         bfu(m[4]) | (bfu(m[5]) << 16));
    recA[(size_t)e*4 + b*2 + 1] = make_uint4(bfu(m[6]) | (bfu(m[7]) << 16), 0u, 0u, 0u);
    recB[(size_t)e*4 + b*2] = make_uint4(__float_as_uint(lb),
                                         bfu(m[8])  | (bfu(m[9])  << 16),
                                         bfu(m[10]) | (bfu(m[11]) << 16),
                                         bfu(m[12]) | (bfu(m[13]) << 16));
    recB[(size_t)e*4 + b*2 + 1] = make_uint4(bfu(m[14]) | (bfu(m[15]) << 16), 0u, 0u, 0u);
}

// ---------------- node: 1 thread = 1 (node,batch); pair threads share rec lines ----------------
__device__ __forceinline__ void aggregate1(int beg, int end, const int* __restrict__ eid,
                                           const uint4* __restrict__ rec, int boff,
                                           float* __restrict__ o) {
    float mx = -1e30f, den = 0.0f, num[CH];
#pragma unroll
    for (int c = 0; c < CH; c++) num[c] = 0.0f;
    for (int i = beg; i < end; ++i) {
        int e = eid[i];
        const uint4* P = rec + (size_t)e*4 + boff;
        uint4 q0 = P[0], q1 = P[1];
        float l = __uint_as_float(q0.x);
        float nm = fmaxf(mx, l);
        float r = __expf(mx - nm), w = __expf(l - nm);
        mx = nm; den = den * r + w;
        float mm[CH];
        mm[0]=ubf(q0.y&0xffffu); mm[1]=ubf(q0.y>>16);
        mm[2]=ubf(q0.z&0xffffu); mm[3]=ubf(q0.z>>16);
        mm[4]=ubf(q0.w&0xffffu); mm[5]=ubf(q0.w>>16);
        mm[6]=ubf(q1.x&0xffffu); mm[7]=ubf(q1.x>>16);
#pragma unroll
        for (int c = 0; c < CH; c++) num[c] = num[c] * r + w * mm[c];
    }
    float inv = 1.0f / (den + 1e-10f);
#pragma unroll
    for (int c = 0; c < CH; c++) o[c] = num[c] * inv;
}

__global__ void __launch_bounds__(256)
node_kernel(const float4* __restrict__ nodesP,
            const int* __restrict__ rowA, const int* __restrict__ rowB,
            const int* __restrict__ eidA, const int* __restrict__ eidB,
            const uint4* __restrict__ recA, const uint4* __restrict__ recB,
            const float* __restrict__ w1, const float* __restrict__ b1,
            const float* __restrict__ w2, const float* __restrict__ b2,
            float* __restrict__ out_nodes) {
    __shared__ float sw1[24*HID], sb1[HID], sw2[HID*CH], sb2[CH];
    int tid = threadIdx.x;
    for (int i = tid; i < 24*HID; i += 256) sw1[i] = w1[i];
    for (int i = tid; i < HID; i += 256) sb1[i] = b1[i];
    for (int i = tid; i < HID*CH; i += 256) sw2[i] = w2[i];
    for (int i = tid; i < CH; i += 256) sb2[i] = b2[i];
    __syncthreads();
    int g = blockIdx.x * 256 + tid;
    int n = g >> 1, b = g & 1;      // pair threads (b=0,1) share rec lines / eid reads
    if (n >= NN) return;

    float in[24];
    float4 np0 = nodesP[(size_t)n*4 + b*2], np1 = nodesP[(size_t)n*4 + b*2 + 1];
    f4w(in, np0); f4w(in + 4, np1);

    aggregate1(rowA[n], rowA[n+1], eidA, recA, b*2, in + 8);
    aggregate1(rowB[n], rowB[n+1], eidB, recB, b*2, in + 16);

    float h[HID];
#pragma unroll
    for (int j = 0; j < HID; j++) {
        float acc = sb1[j];
#pragma unroll
        for (int i = 0; i < 24; i++) acc += in[i] * sw1[i*HID + j];
        h[j] = fast_tanh(acc);
    }
    float no[CH];
#pragma unroll
    for (int k = 0; k < CH; k++) {
        float acc = sb2[k];
#pragma unroll
        for (int j = 0; j < HID; j++) acc += h[j] * sw2[j*CH + k];
        no[k] = soft_clamp(in[k] + acc);
    }
    store8(out_nodes + ((size_t)b*NN + n)*CH, no);
}

extern "C" void kernel_launch(void* const* d_in, const int* in_sizes, int n_in,
                              void* d_out, int out_size, void* d_ws, size_t ws_size,
                              hipStream_t stream) {
    const float* nodes  = (const float*)d_in[0];
    const float* edges  = (const float*)d_in[1];
    const float* msg_w1 = (const float*)d_in[2];
    const float* msg_b1 = (const float*)d_in[3];
    const float* msg_w2 = (const float*)d_in[4];
    const float* msg_b2 = (const float*)d_in[5];
    const float* att_w1 = (const float*)d_in[6];
    const float* att_b1 = (const float*)d_in[7];
    const float* att_w2 = (const float*)d_in[8];
    const float* att_b2 = (const float*)d_in[9];
    const float* upd_w1 = (const float*)d_in[10];
    const float* upd_b1 = (const float*)d_in[11];
    const float* upd_w2 = (const float*)d_in[12];
    const float* upd_b2 = (const float*)d_in[13];
    const int*   sources = (const int*)d_in[14];
    const int*   targets = (const int*)d_in[15];

    float* out       = (float*)d_out;
    float* out_nodes = out;
    float* out_edges = out + (size_t)NB * NN * CH;

    char* wp = (char*)d_ws;
    size_t off = 0;
    auto take = [&](size_t bytes) -> char* {
        char* p = wp + off;
        off = (off + bytes + 255) & ~(size_t)255;
        return p;
    };
    uint4*  S      = (uint4*)take((size_t)NN * NB * 64);
    uint4*  T      = (uint4*)take((size_t)NN * NB * 64);
    float4* nodesP = (float4*)take((size_t)NN * 64);
    int*    cnt    = (int*)take((size_t)2 * NN * 4);
    int*    rowA   = (int*)take((size_t)(NN + 1) * 4);
    int*    rowB   = (int*)take((size_t)(NN + 1) * 4);
    int*    part   = (int*)take((size_t)2 * 256 * 4);
    int*    rankA  = (int*)take((size_t)NE * 4);
    int*    rankB  = (int*)take((size_t)NE * 4);
    int*    eidA   = (int*)take((size_t)NE * 4);
    int*    eidB   = (int*)take((size_t)NE * 4);
    uint4*  recA   = (uint4*)take((size_t)NE * 64);
    uint4*  recB   = (uint4*)take((size_t)NE * 64);
    int* cntA = cnt, *cntB = cnt + NN;

    dim3 gn((NN + 255) / 256, NB);
    dim3 gn2((2*NN + 255) / 256);
    dim3 ge1((NE + 255) / 256);
    dim3 geb(NB, NE / 256);          // batch fastest -> adjacent dispatch of (0,k),(1,k)
    dim3 gs(NTILES, 2);
    dim3 gt(1, 2);

    (void)hipMemsetAsync(cnt, 0, (size_t)2 * NN * 4, stream);
    att_pack_kernel<<<gn, 256, 0, stream>>>(nodes, att_w1, att_b1, att_w2, att_b2,
                                            S, T, nodesP);
    hist_rank_kernel<<<ge1, 256, 0, stream>>>(sources, targets, cntA, cntB, rankA, rankB);
    scan_part_kernel<<<gs, 256, 0, stream>>>(cnt, part);
    scan_top_kernel<<<gt, 256, 0, stream>>>(part, rowA, rowB);
    scan_down_kernel<<<gs, 256, 0, stream>>>(cnt, part, rowA, rowB);
    fill_kernel<<<ge1, 256, 0, stream>>>(sources, targets, rowA, rowB, rankA, rankB,
                                         eidA, eidB);
    edge_kernel<<<geb, 256, 0, stream>>>(S, T, edges, sources, targets,
                                         msg_w1, msg_b1, msg_w2, msg_b2,
                                         out_edges, recA, recB);
    node_kernel<<<gn2, 256, 0, stream>>>(nodesP, rowA, rowB, eidA, eidB, recA, recB,
                                         upd_w1, upd_b1, upd_w2, upd_b2, out_nodes);
}